// Round 10
// baseline (389.370 us; speedup 1.0000x reference)
//
#include <hip/hip_runtime.h>
#include <cstdint>
#include <cstddef>

// ---------------------------------------------------------------------------
// 2-layer GCN, round 10: XCD-affine channel-chunked aggregation.
// hb layout: [8 chunks][N][16ch] bf16 (32B per node per chunk). k_agg blocks
// pick chunk = blockIdx&7 -> with round-robin block->XCD dispatch each XCD
// gathers from a 1.6MB L2-resident slab (vs 12.8MB thrash at r9).
//   k_cvt_w: zero cursor/ovf_cnt + W1,W2 -> bf16 WT[N][K]
//   k_part / k_fill2: ELL-64 build (unchanged from r9)
//   k_gemm_mfma<256,AF32>: hb = bf16((x@W1)*dinv[row]) chunk-major
//   k_agg<BF16OUT=1> -> aggbuf row-major bf16; k_gemm_mfma<128>; k_agg<0>
// ---------------------------------------------------------------------------

#define ELL_STRIDE 64
#define BCAP 8192
#define OVF_CAP 1024
#define PART_T 2048

typedef __attribute__((ext_vector_type(8))) short bf16x8;
typedef __attribute__((ext_vector_type(4))) float floatx4;

__device__ __forceinline__ unsigned short f2bf(float f) {
  unsigned int u = __float_as_uint(f);
  unsigned int r = (u + 0x7fffu + ((u >> 16) & 1u)) >> 16;   // RNE
  return (unsigned short)r;
}
__device__ __forceinline__ float2 bfpair(unsigned int p) {
  float2 r;
  r.x = __uint_as_float(p << 16);
  r.y = __uint_as_float(p & 0xffff0000u);
  return r;
}

// ---------------- zero workspace + W -> bf16 transposed [N=128][K] --------
__global__ __launch_bounds__(256) void k_cvt_w(const float* __restrict__ W1,
                                               const float* __restrict__ W2,
                                               unsigned short* __restrict__ WT1,
                                               unsigned short* __restrict__ WT2,
                                               int* __restrict__ cursor,
                                               int* __restrict__ ovf_cnt,
                                               int NB) {
  int i = blockIdx.x * 256 + threadIdx.x;
  if (i < NB) cursor[i] = 0;
  if (i == NB) *ovf_cnt = 0;
  if (i < 128 * 256) {                 // WT1[n][k] = W1[k][n], K=256
    int n = i >> 8, k = i & 255;
    WT1[i] = f2bf(W1[k * 128 + n]);
  } else if (i < 128 * 256 + 128 * 128) {
    int j = i - 128 * 256;             // WT2[n][k] = W2[k][n], K=128
    int n = j >> 7, k = j & 127;
    WT2[j] = f2bf(W2[k * 128 + n]);
  }
}

// ---------------- phase 1: bucket partition ----------------
__global__ __launch_bounds__(256) void k_part(const int* __restrict__ src,
                                              const int* __restrict__ dst,
                                              int* __restrict__ cursor,
                                              unsigned int* __restrict__ part,
                                              int* __restrict__ ovf_cnt,
                                              int* __restrict__ ovf,
                                              int E, int NB) {
  __shared__ unsigned int stage1[PART_T];
  __shared__ unsigned int stage2[PART_T];
  __shared__ int hist[512];
  __shared__ int base_g[512];
  __shared__ int base_l[512];
  __shared__ int cl[512];
  __shared__ int sc[256];
  const int tid = threadIdx.x;
  const int e0 = blockIdx.x * PART_T;
  int valid = E - e0; if (valid > PART_T) valid = PART_T;

  hist[tid] = 0; hist[tid + 256] = 0;
  cl[tid] = 0; cl[tid + 256] = 0;
  __syncthreads();
  for (int i = tid; i < valid; i += 256) {
    int e = e0 + i;
    unsigned int v = (unsigned int)(src[e] & 0xffff) | ((unsigned int)dst[e] << 16);
    stage1[i] = v;
    atomicAdd(&hist[(v >> 16) >> 7], 1);
  }
  __syncthreads();
  for (int b = tid; b < NB; b += 256) base_g[b] = atomicAdd(&cursor[b], hist[b]);
  int h0 = hist[2 * tid], h1 = hist[2 * tid + 1];
  int pv = h0 + h1;
  sc[tid] = pv;
  __syncthreads();
  #pragma unroll
  for (int off = 1; off < 256; off <<= 1) {
    int t = (tid >= off) ? sc[tid - off] : 0;
    __syncthreads();
    sc[tid] += t;
    __syncthreads();
  }
  int excl = sc[tid] - pv;
  base_l[2 * tid] = excl;
  base_l[2 * tid + 1] = excl + h0;
  __syncthreads();
  for (int i = tid; i < valid; i += 256) {
    unsigned int v = stage1[i];
    int b = (v >> 16) >> 7;
    int pos = base_l[b] + atomicAdd(&cl[b], 1);
    stage2[pos] = v;
  }
  __syncthreads();
  for (int i = tid; i < valid; i += 256) {
    unsigned int v = stage2[i];
    int b = (v >> 16) >> 7;
    int g = base_g[b] + (i - base_l[b]);
    if (g < BCAP) {
      part[(size_t)b * BCAP + g] = v;
    } else {
      int p = atomicAdd(ovf_cnt, 1);
      if (p < OVF_CAP) { ovf[2 * p] = (int)(v & 0xffffu); ovf[2 * p + 1] = (int)(v >> 16); }
    }
  }
}

// ---------------- phase 2: per-bucket ELL build in LDS ----------------
__global__ __launch_bounds__(256) void k_fill2(const unsigned int* __restrict__ part,
                                               const int* __restrict__ cursor,
                                               unsigned short* __restrict__ col,
                                               int* __restrict__ cnt,
                                               float* __restrict__ dinv,
                                               int* __restrict__ ovf_cnt,
                                               int* __restrict__ ovf, int N) {
  __shared__ unsigned short slab[128 * ELL_STRIDE];  // 16 KB
  __shared__ int cl[128];
  const int tid = threadIdx.x;
  const int b = blockIdx.x;
  if (tid < 128) cl[tid] = 0;
  __syncthreads();
  int count = cursor[b]; if (count > BCAP) count = BCAP;
  const unsigned int* p = part + (size_t)b * BCAP;
  for (int i = tid; i < count; i += 256) {
    unsigned int v = p[i];
    int row = (v >> 16) & 127;
    int k = atomicAdd(&cl[row], 1);
    if (k < ELL_STRIDE) {
      slab[row * ELL_STRIDE + k] = (unsigned short)(v & 0xffffu);
    } else {
      int q = atomicAdd(ovf_cnt, 1);
      if (q < OVF_CAP) { ovf[2 * q] = (int)(v & 0xffffu); ovf[2 * q + 1] = (int)(v >> 16); }
    }
  }
  __syncthreads();
  uint4* d4 = (uint4*)(col + (size_t)b * 128 * ELL_STRIDE);
  const uint4* s4 = (const uint4*)slab;
  #pragma unroll
  for (int i = 0; i < (128 * ELL_STRIDE * 2) / (16 * 256); ++i)
    d4[i * 256 + tid] = s4[i * 256 + tid];
  if (tid < 128) {
    int node = b * 128 + tid;
    if (node < N) {
      int c = cl[tid];
      cnt[node] = c;
      dinv[node] = rsqrtf((float)c + 1.0f);
    }
  }
}

// ---------------- MFMA GEMM -> chunk-major hb ----------------
// B staged in LDS (two 64-row halves, +8-short row pad). Epilogue writes
// hb[chunk=nt][row][m] (channel nt*16+m), pre-scaled by dinv[row].
template <int K, bool AF32>
__global__ __launch_bounds__(256) void k_gemm_mfma(const void* __restrict__ Xv,
                                                   const unsigned short* __restrict__ WT,
                                                   const float* __restrict__ dinv,
                                                   unsigned short* __restrict__ hb,
                                                   int M) {
  constexpr int KP = K + 8;
  __shared__ unsigned short Bs[64 * KP];
  const int tid = threadIdx.x;
  const int wave = tid >> 6, lane = tid & 63;
  const int q = lane >> 4, m = lane & 15;
  const int row0 = blockIdx.x * 64 + wave * 16;
  const bool active = row0 < M;
  const int arow = row0 + m;

  floatx4 acc[8];
  #pragma unroll
  for (int nt = 0; nt < 8; ++nt) acc[nt] = (floatx4){0.f, 0.f, 0.f, 0.f};
  bf16x8 af[K / 32];

  #pragma unroll
  for (int half = 0; half < 2; ++half) {
    __syncthreads();
    for (int c = tid; c < 64 * (K / 8); c += 256) {
      int r = c / (K / 8), ko = (c % (K / 8)) * 8;
      *(uint4*)(Bs + r * KP + ko) =
          *(const uint4*)(WT + (size_t)(half * 64 + r) * K + ko);
    }
    __syncthreads();
    if (active) {
      #pragma unroll
      for (int ks = 0; ks < K / 32; ++ks) {
        const int k0 = ks * 32 + q * 8;
        if (half == 0) {
          if (AF32) {
            const float* X = (const float*)Xv;
            float4 a0 = *(const float4*)(X + (size_t)arow * K + k0);
            float4 a1 = *(const float4*)(X + (size_t)arow * K + k0 + 4);
            af[ks] = (bf16x8){(short)f2bf(a0.x), (short)f2bf(a0.y),
                              (short)f2bf(a0.z), (short)f2bf(a0.w),
                              (short)f2bf(a1.x), (short)f2bf(a1.y),
                              (short)f2bf(a1.z), (short)f2bf(a1.w)};
          } else {
            af[ks] = *(const bf16x8*)((const unsigned short*)Xv +
                                      (size_t)arow * K + k0);
          }
        }
        #pragma unroll
        for (int ntl = 0; ntl < 4; ++ntl) {
          bf16x8 bf = *(const bf16x8*)(Bs + (ntl * 16 + m) * KP + k0);
          acc[half * 4 + ntl] =
              __builtin_amdgcn_mfma_f32_16x16x32_bf16(af[ks], bf, acc[half * 4 + ntl],
                                                      0, 0, 0);
        }
      }
    }
  }
  if (!active) return;
  #pragma unroll
  for (int r = 0; r < 4; ++r) {
    int grow = row0 + q * 4 + r;
    float di = dinv[grow];
    #pragma unroll
    for (int nt = 0; nt < 8; ++nt)
      hb[(size_t)nt * M * 16 + (size_t)grow * 16 + m] = f2bf(acc[nt][r] * di);
  }
}

// ---------------- XCD-affine chunked ELL aggregate + bias + ReLU ----------
// chunk = blockIdx&7 (one 1.6MB hb slab per XCD under round-robin dispatch).
// wave = 1 dst node: lane = (edge slot e = lane>>3) x (uint u = lane&7);
// per step 8 edges x 32B rows gathered, cols shfl-distributed from preload.
template <bool BF16OUT>
__global__ __launch_bounds__(256) void k_agg(const unsigned int* __restrict__ hb,
                                             const int* __restrict__ cnt,
                                             const unsigned short* __restrict__ col,
                                             const float* __restrict__ dinv,
                                             const int* __restrict__ ovf_cnt,
                                             const int* __restrict__ ovf,
                                             const float* __restrict__ bias,
                                             void* __restrict__ outv, int n) {
  const int wave = threadIdx.x >> 6, lane = threadIdx.x & 63;
  const int chunk = blockIdx.x & 7;
  const int d = (blockIdx.x >> 3) * 4 + wave;
  if (d >= n) return;
  const int e = lane >> 3, u = lane & 7;
  const unsigned int* slab = hb + (size_t)chunk * n * 8;

  int m = cnt[d]; if (m > ELL_STRIDE) m = ELL_STRIDE;
  int cv = (lane < m) ? (int)col[(size_t)d * ELL_STRIDE + lane] : d;

  float2 acc = make_float2(0.f, 0.f);
  if (e == 0) {   // self-loop: hb pre-scaled by dinv -> hb[d]*dinv[d]
    float2 v = bfpair(slab[(size_t)d * 8 + u]);
    acc.x += v.x; acc.y += v.y;
  }
  for (int k0 = 0; k0 < m; k0 += 16) {   // 2 steps -> 16 rows in flight
    int i0 = k0 + e, i1 = k0 + 8 + e;    // always < 64
    int c0 = __shfl(cv, i0);
    int c1 = __shfl(cv, i1);
    unsigned int p0 = slab[(size_t)c0 * 8 + u];
    unsigned int p1 = slab[(size_t)c1 * 8 + u];
    float2 v0 = bfpair(p0), v1 = bfpair(p1);
    if (i0 < m) { acc.x += v0.x; acc.y += v0.y; }
    if (i1 < m) { acc.x += v1.x; acc.y += v1.y; }
  }
  if (e == 0) {
    int V = *ovf_cnt; if (V > OVF_CAP) V = OVF_CAP;
    for (int j = 0; j < V; ++j) {
      if (ovf[2 * j + 1] == d) {
        float2 v = bfpair(slab[(size_t)ovf[2 * j] * 8 + u]);
        acc.x += v.x; acc.y += v.y;
      }
    }
  }
  acc.x += __shfl_xor(acc.x, 8);  acc.y += __shfl_xor(acc.y, 8);
  acc.x += __shfl_xor(acc.x, 16); acc.y += __shfl_xor(acc.y, 16);
  acc.x += __shfl_xor(acc.x, 32); acc.y += __shfl_xor(acc.y, 32);
  if (e == 0) {
    float di = dinv[d];
    float2 bv = *(const float2*)(bias + chunk * 16 + 2 * u);
    float rx = fmaxf(di * acc.x + bv.x, 0.f);
    float ry = fmaxf(di * acc.y + bv.y, 0.f);
    if (BF16OUT) {   // row-major [N][128] bf16 for gemm2's A
      unsigned int pk = (unsigned int)f2bf(rx) | ((unsigned int)f2bf(ry) << 16);
      ((unsigned int*)outv)[(size_t)d * 64 + chunk * 8 + u] = pk;
    } else {
      *(float2*)((float*)outv + (size_t)d * 128 + chunk * 16 + 2 * u) =
          make_float2(rx, ry);
    }
  }
}

// ---------------------------------------------------------------------------
extern "C" void kernel_launch(void* const* d_in, const int* in_sizes, int n_in,
                              void* d_out, int out_size, void* d_ws, size_t ws_size,
                              hipStream_t stream) {
  const float* x  = (const float*)d_in[0];
  const int*   ei = (const int*)d_in[1];
  const float* W1 = (const float*)d_in[2];
  const float* b1 = (const float*)d_in[3];
  const float* W2 = (const float*)d_in[4];
  const float* b2 = (const float*)d_in[5];
  float* out = (float*)d_out;

  const int IN_CH = 256;
  const int N = in_sizes[0] / IN_CH;   // 50000
  const int E = in_sizes[1] / 2;       // 1,600,000
  const int NB = (N + 127) >> 7;       // 391 buckets

  const int* src = ei;
  const int* dst = ei + E;

  char* ws = (char*)d_ws;
  size_t off = 0;
  auto carve = [&](size_t bytes) {
    void* p = ws + off;
    off += (bytes + 255) & ~(size_t)255;
    return p;
  };
  int*            cursor  = (int*)carve((size_t)NB * 4);
  int*            ovf_cnt = (int*)carve(4);
  int*            ovf     = (int*)carve((size_t)OVF_CAP * 2 * 4);
  int*            cnt     = (int*)carve((size_t)N * 4);
  float*          dinv    = (float*)carve((size_t)N * 4);
  unsigned short* col     = (unsigned short*)carve((size_t)N * ELL_STRIDE * 2); // 6.4MB
  unsigned short* hb      = (unsigned short*)carve((size_t)N * 128 * 2);        // [8][N][16] 12.8MB
  unsigned short* WT1     = (unsigned short*)carve(128 * 256 * 2);
  unsigned short* WT2     = (unsigned short*)carve(128 * 128 * 2);
  // union: part (dead after k_fill2) aliases aggbuf (bf16, by k_agg#1)
  char*           unionp  = (char*)carve((size_t)NB * BCAP * 4);   // 12.8MB
  unsigned int*   part    = (unsigned int*)unionp;
  unsigned short* aggbuf  = (unsigned short*)unionp;               // [N][128] bf16

  k_cvt_w<<<(128 * 256 + 128 * 128 + 255) / 256, 256, 0, stream>>>(
      W1, W2, WT1, WT2, cursor, ovf_cnt, NB);
  k_part <<<(E + PART_T - 1) / PART_T, 256, 0, stream>>>(src, dst, cursor, part,
                                                         ovf_cnt, ovf, E, NB);
  k_fill2<<<NB, 256, 0, stream>>>(part, cursor, col, cnt, dinv, ovf_cnt, ovf, N);

  int gblocks = (N + 63) / 64;         // 782
  int ablocks = 8 * ((N + 3) / 4);     // 8 chunks x 12500
  k_gemm_mfma<256, true ><<<gblocks, 256, 0, stream>>>(x, WT1, dinv, hb, N);
  k_agg<true ><<<ablocks, 256, 0, stream>>>((const unsigned int*)hb, cnt, col, dinv,
                                            ovf_cnt, ovf, b1, aggbuf, N);
  k_gemm_mfma<128, false><<<gblocks, 256, 0, stream>>>(aggbuf, WT2, dinv, hb, N);
  k_agg<false><<<ablocks, 256, 0, stream>>>((const unsigned int*)hb, cnt, col, dinv,
                                            ovf_cnt, ovf, b2, out, N);
}

// Round 11
// 266.538 us; speedup vs baseline: 1.4608x; 1.4608x over previous
//
#include <hip/hip_runtime.h>
#include <cstdint>
#include <cstddef>

// ---------------------------------------------------------------------------
// 2-layer GCN, round 11: XCD-affine 4-chunk agg with r9's VALU profile.
// hb layout: [4 chunks][N][32ch] bf16 (64B/node/chunk). k_agg: chunk =
// blockIdx&3 (slab 3.2MB -> ~2 XCDs' L2 under round-robin dispatch);
// quarter-wave (16 lanes) = 1 node, lane = uint (2ch), edges sequential,
// 8-deep unrolled independent gathers, NO shfl/reduction/conditional adds.
//   k_cvt_w: zero cursor/ovf_cnt + W1,W2 -> bf16 WT[N][K]
//   k_part / k_fill2: ELL-64 build (unchanged from r9)
//   k_gemm_mfma<256,AF32>: hb = bf16((x@W1)*dinv[row]) chunk-major
//   k_agg<BF16OUT=1> -> aggbuf row-major bf16; k_gemm_mfma<128>; k_agg<0>
// ---------------------------------------------------------------------------

#define ELL_STRIDE 64
#define BCAP 8192
#define OVF_CAP 1024
#define PART_T 2048

typedef __attribute__((ext_vector_type(8))) short bf16x8;
typedef __attribute__((ext_vector_type(4))) float floatx4;

__device__ __forceinline__ unsigned short f2bf(float f) {
  unsigned int u = __float_as_uint(f);
  unsigned int r = (u + 0x7fffu + ((u >> 16) & 1u)) >> 16;   // RNE
  return (unsigned short)r;
}
__device__ __forceinline__ float2 bfpair(unsigned int p) {
  float2 r;
  r.x = __uint_as_float(p << 16);
  r.y = __uint_as_float(p & 0xffff0000u);
  return r;
}

// ---------------- zero workspace + W -> bf16 transposed [N=128][K] --------
__global__ __launch_bounds__(256) void k_cvt_w(const float* __restrict__ W1,
                                               const float* __restrict__ W2,
                                               unsigned short* __restrict__ WT1,
                                               unsigned short* __restrict__ WT2,
                                               int* __restrict__ cursor,
                                               int* __restrict__ ovf_cnt,
                                               int NB) {
  int i = blockIdx.x * 256 + threadIdx.x;
  if (i < NB) cursor[i] = 0;
  if (i == NB) *ovf_cnt = 0;
  if (i < 128 * 256) {                 // WT1[n][k] = W1[k][n], K=256
    int n = i >> 8, k = i & 255;
    WT1[i] = f2bf(W1[k * 128 + n]);
  } else if (i < 128 * 256 + 128 * 128) {
    int j = i - 128 * 256;             // WT2[n][k] = W2[k][n], K=128
    int n = j >> 7, k = j & 127;
    WT2[j] = f2bf(W2[k * 128 + n]);
  }
}

// ---------------- phase 1: bucket partition ----------------
__global__ __launch_bounds__(256) void k_part(const int* __restrict__ src,
                                              const int* __restrict__ dst,
                                              int* __restrict__ cursor,
                                              unsigned int* __restrict__ part,
                                              int* __restrict__ ovf_cnt,
                                              int* __restrict__ ovf,
                                              int E, int NB) {
  __shared__ unsigned int stage1[PART_T];
  __shared__ unsigned int stage2[PART_T];
  __shared__ int hist[512];
  __shared__ int base_g[512];
  __shared__ int base_l[512];
  __shared__ int cl[512];
  __shared__ int sc[256];
  const int tid = threadIdx.x;
  const int e0 = blockIdx.x * PART_T;
  int valid = E - e0; if (valid > PART_T) valid = PART_T;

  hist[tid] = 0; hist[tid + 256] = 0;
  cl[tid] = 0; cl[tid + 256] = 0;
  __syncthreads();
  for (int i = tid; i < valid; i += 256) {
    int e = e0 + i;
    unsigned int v = (unsigned int)(src[e] & 0xffff) | ((unsigned int)dst[e] << 16);
    stage1[i] = v;
    atomicAdd(&hist[(v >> 16) >> 7], 1);
  }
  __syncthreads();
  for (int b = tid; b < NB; b += 256) base_g[b] = atomicAdd(&cursor[b], hist[b]);
  int h0 = hist[2 * tid], h1 = hist[2 * tid + 1];
  int pv = h0 + h1;
  sc[tid] = pv;
  __syncthreads();
  #pragma unroll
  for (int off = 1; off < 256; off <<= 1) {
    int t = (tid >= off) ? sc[tid - off] : 0;
    __syncthreads();
    sc[tid] += t;
    __syncthreads();
  }
  int excl = sc[tid] - pv;
  base_l[2 * tid] = excl;
  base_l[2 * tid + 1] = excl + h0;
  __syncthreads();
  for (int i = tid; i < valid; i += 256) {
    unsigned int v = stage1[i];
    int b = (v >> 16) >> 7;
    int pos = base_l[b] + atomicAdd(&cl[b], 1);
    stage2[pos] = v;
  }
  __syncthreads();
  for (int i = tid; i < valid; i += 256) {
    unsigned int v = stage2[i];
    int b = (v >> 16) >> 7;
    int g = base_g[b] + (i - base_l[b]);
    if (g < BCAP) {
      part[(size_t)b * BCAP + g] = v;
    } else {
      int p = atomicAdd(ovf_cnt, 1);
      if (p < OVF_CAP) { ovf[2 * p] = (int)(v & 0xffffu); ovf[2 * p + 1] = (int)(v >> 16); }
    }
  }
}

// ---------------- phase 2: per-bucket ELL build in LDS ----------------
__global__ __launch_bounds__(256) void k_fill2(const unsigned int* __restrict__ part,
                                               const int* __restrict__ cursor,
                                               unsigned short* __restrict__ col,
                                               int* __restrict__ cnt,
                                               float* __restrict__ dinv,
                                               int* __restrict__ ovf_cnt,
                                               int* __restrict__ ovf, int N) {
  __shared__ unsigned short slab[128 * ELL_STRIDE];  // 16 KB
  __shared__ int cl[128];
  const int tid = threadIdx.x;
  const int b = blockIdx.x;
  if (tid < 128) cl[tid] = 0;
  __syncthreads();
  int count = cursor[b]; if (count > BCAP) count = BCAP;
  const unsigned int* p = part + (size_t)b * BCAP;
  for (int i = tid; i < count; i += 256) {
    unsigned int v = p[i];
    int row = (v >> 16) & 127;
    int k = atomicAdd(&cl[row], 1);
    if (k < ELL_STRIDE) {
      slab[row * ELL_STRIDE + k] = (unsigned short)(v & 0xffffu);
    } else {
      int q = atomicAdd(ovf_cnt, 1);
      if (q < OVF_CAP) { ovf[2 * q] = (int)(v & 0xffffu); ovf[2 * q + 1] = (int)(v >> 16); }
    }
  }
  __syncthreads();
  uint4* d4 = (uint4*)(col + (size_t)b * 128 * ELL_STRIDE);
  const uint4* s4 = (const uint4*)slab;
  #pragma unroll
  for (int i = 0; i < (128 * ELL_STRIDE * 2) / (16 * 256); ++i)
    d4[i * 256 + tid] = s4[i * 256 + tid];
  if (tid < 128) {
    int node = b * 128 + tid;
    if (node < N) {
      int c = cl[tid];
      cnt[node] = c;
      dinv[node] = rsqrtf((float)c + 1.0f);
    }
  }
}

// ---------------- MFMA GEMM -> chunk-major hb [4][M][32ch] ----------------
// B staged in LDS (two 64-row halves, +8-short row pad). Epilogue writes
// channel nt*16+m at hb[(nt>>1)][row][(nt&1)*16+m], pre-scaled by dinv[row].
template <int K, bool AF32>
__global__ __launch_bounds__(256) void k_gemm_mfma(const void* __restrict__ Xv,
                                                   const unsigned short* __restrict__ WT,
                                                   const float* __restrict__ dinv,
                                                   unsigned short* __restrict__ hb,
                                                   int M) {
  constexpr int KP = K + 8;
  __shared__ unsigned short Bs[64 * KP];
  const int tid = threadIdx.x;
  const int wave = tid >> 6, lane = tid & 63;
  const int q = lane >> 4, m = lane & 15;
  const int row0 = blockIdx.x * 64 + wave * 16;
  const bool active = row0 < M;
  const int arow = row0 + m;

  floatx4 acc[8];
  #pragma unroll
  for (int nt = 0; nt < 8; ++nt) acc[nt] = (floatx4){0.f, 0.f, 0.f, 0.f};
  bf16x8 af[K / 32];

  #pragma unroll
  for (int half = 0; half < 2; ++half) {
    __syncthreads();
    for (int c = tid; c < 64 * (K / 8); c += 256) {
      int r = c / (K / 8), ko = (c % (K / 8)) * 8;
      *(uint4*)(Bs + r * KP + ko) =
          *(const uint4*)(WT + (size_t)(half * 64 + r) * K + ko);
    }
    __syncthreads();
    if (active) {
      #pragma unroll
      for (int ks = 0; ks < K / 32; ++ks) {
        const int k0 = ks * 32 + q * 8;
        if (half == 0) {
          if (AF32) {
            const float* X = (const float*)Xv;
            float4 a0 = *(const float4*)(X + (size_t)arow * K + k0);
            float4 a1 = *(const float4*)(X + (size_t)arow * K + k0 + 4);
            af[ks] = (bf16x8){(short)f2bf(a0.x), (short)f2bf(a0.y),
                              (short)f2bf(a0.z), (short)f2bf(a0.w),
                              (short)f2bf(a1.x), (short)f2bf(a1.y),
                              (short)f2bf(a1.z), (short)f2bf(a1.w)};
          } else {
            af[ks] = *(const bf16x8*)((const unsigned short*)Xv +
                                      (size_t)arow * K + k0);
          }
        }
        #pragma unroll
        for (int ntl = 0; ntl < 4; ++ntl) {
          bf16x8 bf = *(const bf16x8*)(Bs + (ntl * 16 + m) * KP + k0);
          acc[half * 4 + ntl] =
              __builtin_amdgcn_mfma_f32_16x16x32_bf16(af[ks], bf, acc[half * 4 + ntl],
                                                      0, 0, 0);
        }
      }
    }
  }
  if (!active) return;
  #pragma unroll
  for (int r = 0; r < 4; ++r) {
    int grow = row0 + q * 4 + r;
    float di = dinv[grow];
    #pragma unroll
    for (int nt = 0; nt < 8; ++nt)
      hb[(size_t)(nt >> 1) * M * 32 + (size_t)grow * 32 + (nt & 1) * 16 + m] =
          f2bf(acc[nt][r] * di);
  }
}

// ---------------- XCD-affine 4-chunk ELL aggregate + bias + ReLU ----------
// chunk = blockIdx&3; block = 16 nodes (4 waves x 4 quarter-nodes).
// Quarter-wave = 1 node: 16 lanes own the chunk's 16 uints (2ch each);
// edges sequential with 8-deep unrolled independent 64B row-gathers.
template <bool BF16OUT>
__global__ __launch_bounds__(256) void k_agg(const unsigned int* __restrict__ hb,
                                             const int* __restrict__ cnt,
                                             const unsigned short* __restrict__ col,
                                             const float* __restrict__ dinv,
                                             const int* __restrict__ ovf_cnt,
                                             const int* __restrict__ ovf,
                                             const float* __restrict__ bias,
                                             void* __restrict__ outv, int n) {
  const int tid = threadIdx.x;
  const int chunk = blockIdx.x & 3;
  const int nb = blockIdx.x >> 2;
  const int d = nb * 16 + (tid >> 4);    // quarter-wave -> node
  const int u = tid & 15;                // uint (2ch) within 32-ch chunk
  if (d >= n) return;
  const unsigned int* slab = hb + (size_t)chunk * n * 16;

  // self-loop: hb pre-scaled by dinv -> hb[d]*dinv[d] = h[d]*dinv^2
  float2 acc = bfpair(slab[(size_t)d * 16 + u]);

  int m = cnt[d]; if (m > ELL_STRIDE) m = ELL_STRIDE;
  const unsigned short* crow = col + (size_t)d * ELL_STRIDE;
  int k = 0;
  for (; k + 8 <= m; k += 8) {
    ushort4 ca = *(const ushort4*)(crow + k);
    ushort4 cb = *(const ushort4*)(crow + k + 4);
    unsigned int p0 = slab[(size_t)ca.x * 16 + u];
    unsigned int p1 = slab[(size_t)ca.y * 16 + u];
    unsigned int p2 = slab[(size_t)ca.z * 16 + u];
    unsigned int p3 = slab[(size_t)ca.w * 16 + u];
    unsigned int p4 = slab[(size_t)cb.x * 16 + u];
    unsigned int p5 = slab[(size_t)cb.y * 16 + u];
    unsigned int p6 = slab[(size_t)cb.z * 16 + u];
    unsigned int p7 = slab[(size_t)cb.w * 16 + u];
    float2 v0 = bfpair(p0), v1 = bfpair(p1), v2 = bfpair(p2), v3 = bfpair(p3);
    float2 v4 = bfpair(p4), v5 = bfpair(p5), v6 = bfpair(p6), v7 = bfpair(p7);
    acc.x += v0.x + v1.x + v2.x + v3.x + v4.x + v5.x + v6.x + v7.x;
    acc.y += v0.y + v1.y + v2.y + v3.y + v4.y + v5.y + v6.y + v7.y;
  }
  for (; k < m; ++k) {
    int c = crow[k];
    float2 v = bfpair(slab[(size_t)c * 16 + u]);
    acc.x += v.x; acc.y += v.y;
  }
  int V = *ovf_cnt; if (V > OVF_CAP) V = OVF_CAP;
  for (int j = 0; j < V; ++j) {
    if (ovf[2 * j + 1] == d) {
      float2 v = bfpair(slab[(size_t)ovf[2 * j] * 16 + u]);
      acc.x += v.x; acc.y += v.y;
    }
  }
  float di = dinv[d];
  float2 bv = *(const float2*)(bias + chunk * 32 + 2 * u);
  float rx = fmaxf(di * acc.x + bv.x, 0.f);
  float ry = fmaxf(di * acc.y + bv.y, 0.f);
  if (BF16OUT) {   // row-major [N][128] bf16 (true channel order) for gemm2
    unsigned int pk = (unsigned int)f2bf(rx) | ((unsigned int)f2bf(ry) << 16);
    ((unsigned int*)outv)[(size_t)d * 64 + chunk * 16 + u] = pk;
  } else {
    *(float2*)((float*)outv + (size_t)d * 128 + chunk * 32 + 2 * u) =
        make_float2(rx, ry);
  }
}

// ---------------------------------------------------------------------------
extern "C" void kernel_launch(void* const* d_in, const int* in_sizes, int n_in,
                              void* d_out, int out_size, void* d_ws, size_t ws_size,
                              hipStream_t stream) {
  const float* x  = (const float*)d_in[0];
  const int*   ei = (const int*)d_in[1];
  const float* W1 = (const float*)d_in[2];
  const float* b1 = (const float*)d_in[3];
  const float* W2 = (const float*)d_in[4];
  const float* b2 = (const float*)d_in[5];
  float* out = (float*)d_out;

  const int IN_CH = 256;
  const int N = in_sizes[0] / IN_CH;   // 50000
  const int E = in_sizes[1] / 2;       // 1,600,000
  const int NB = (N + 127) >> 7;       // 391 buckets

  const int* src = ei;
  const int* dst = ei + E;

  char* ws = (char*)d_ws;
  size_t off = 0;
  auto carve = [&](size_t bytes) {
    void* p = ws + off;
    off += (bytes + 255) & ~(size_t)255;
    return p;
  };
  int*            cursor  = (int*)carve((size_t)NB * 4);
  int*            ovf_cnt = (int*)carve(4);
  int*            ovf     = (int*)carve((size_t)OVF_CAP * 2 * 4);
  int*            cnt     = (int*)carve((size_t)N * 4);
  float*          dinv    = (float*)carve((size_t)N * 4);
  unsigned short* col     = (unsigned short*)carve((size_t)N * ELL_STRIDE * 2); // 6.4MB
  unsigned short* hb      = (unsigned short*)carve((size_t)N * 128 * 2);        // [4][N][32] 12.8MB
  unsigned short* WT1     = (unsigned short*)carve(128 * 256 * 2);
  unsigned short* WT2     = (unsigned short*)carve(128 * 128 * 2);
  // union: part (dead after k_fill2) aliases aggbuf (bf16, by k_agg#1)
  char*           unionp  = (char*)carve((size_t)NB * BCAP * 4);   // 12.8MB
  unsigned int*   part    = (unsigned int*)unionp;
  unsigned short* aggbuf  = (unsigned short*)unionp;               // [N][128] bf16

  k_cvt_w<<<(128 * 256 + 128 * 128 + 255) / 256, 256, 0, stream>>>(
      W1, W2, WT1, WT2, cursor, ovf_cnt, NB);
  k_part <<<(E + PART_T - 1) / PART_T, 256, 0, stream>>>(src, dst, cursor, part,
                                                         ovf_cnt, ovf, E, NB);
  k_fill2<<<NB, 256, 0, stream>>>(part, cursor, col, cnt, dinv, ovf_cnt, ovf, N);

  int gblocks = (N + 63) / 64;           // 782
  int ablocks = 4 * ((N + 15) / 16);     // 4 chunks x 3125
  k_gemm_mfma<256, true ><<<gblocks, 256, 0, stream>>>(x, WT1, dinv, hb, N);
  k_agg<true ><<<ablocks, 256, 0, stream>>>((const unsigned int*)hb, cnt, col, dinv,
                                            ovf_cnt, ovf, b1, aggbuf, N);
  k_gemm_mfma<128, false><<<gblocks, 256, 0, stream>>>(aggbuf, WT2, dinv, hb, N);
  k_agg<false><<<ablocks, 256, 0, stream>>>((const unsigned int*)hb, cnt, col, dinv,
                                            ovf_cnt, ovf, b2, out, N);
}

// Round 12
// 247.411 us; speedup vs baseline: 1.5738x; 1.0773x over previous
//
#include <hip/hip_runtime.h>
#include <cstdint>
#include <cstddef>

// ---------------------------------------------------------------------------
// 2-layer GCN, round 12: r11 + LDS-staged col lists + 16-deep gather MLP.
// hb layout: [4 chunks][N][32ch] bf16. k_agg: chunk=blockIdx&3 (3.2MB slab,
// XCD-affine), quarter-wave = 1 node, cols preloaded to LDS (broadcast reads,
// no global col load in the edge loop), 16 independent gathers in flight.
//   k_cvt_w: zero cursor/ovf_cnt + W1,W2 -> bf16 WT[N][K]
//   k_part / k_fill2: ELL-64 build
//   k_gemm_mfma<256,AF32>: hb = bf16((x@W1)*dinv[row]) chunk-major, B in LDS
//   k_agg<BF16OUT=1> -> aggbuf row-major bf16; k_gemm_mfma<128>; k_agg<0>
// ---------------------------------------------------------------------------

#define ELL_STRIDE 64
#define BCAP 8192
#define OVF_CAP 1024
#define PART_T 2048

typedef __attribute__((ext_vector_type(8))) short bf16x8;
typedef __attribute__((ext_vector_type(4))) float floatx4;

__device__ __forceinline__ unsigned short f2bf(float f) {
  unsigned int u = __float_as_uint(f);
  unsigned int r = (u + 0x7fffu + ((u >> 16) & 1u)) >> 16;   // RNE
  return (unsigned short)r;
}
__device__ __forceinline__ float2 bfpair(unsigned int p) {
  float2 r;
  r.x = __uint_as_float(p << 16);
  r.y = __uint_as_float(p & 0xffff0000u);
  return r;
}

// ---------------- zero workspace + W -> bf16 transposed [N=128][K] --------
__global__ __launch_bounds__(256) void k_cvt_w(const float* __restrict__ W1,
                                               const float* __restrict__ W2,
                                               unsigned short* __restrict__ WT1,
                                               unsigned short* __restrict__ WT2,
                                               int* __restrict__ cursor,
                                               int* __restrict__ ovf_cnt,
                                               int NB) {
  int i = blockIdx.x * 256 + threadIdx.x;
  if (i < NB) cursor[i] = 0;
  if (i == NB) *ovf_cnt = 0;
  if (i < 128 * 256) {                 // WT1[n][k] = W1[k][n], K=256
    int n = i >> 8, k = i & 255;
    WT1[i] = f2bf(W1[k * 128 + n]);
  } else if (i < 128 * 256 + 128 * 128) {
    int j = i - 128 * 256;             // WT2[n][k] = W2[k][n], K=128
    int n = j >> 7, k = j & 127;
    WT2[j] = f2bf(W2[k * 128 + n]);
  }
}

// ---------------- phase 1: bucket partition ----------------
__global__ __launch_bounds__(256) void k_part(const int* __restrict__ src,
                                              const int* __restrict__ dst,
                                              int* __restrict__ cursor,
                                              unsigned int* __restrict__ part,
                                              int* __restrict__ ovf_cnt,
                                              int* __restrict__ ovf,
                                              int E, int NB) {
  __shared__ unsigned int stage1[PART_T];
  __shared__ unsigned int stage2[PART_T];
  __shared__ int hist[512];
  __shared__ int base_g[512];
  __shared__ int base_l[512];
  __shared__ int cl[512];
  __shared__ int sc[256];
  const int tid = threadIdx.x;
  const int e0 = blockIdx.x * PART_T;
  int valid = E - e0; if (valid > PART_T) valid = PART_T;

  hist[tid] = 0; hist[tid + 256] = 0;
  cl[tid] = 0; cl[tid + 256] = 0;
  __syncthreads();
  for (int i = tid; i < valid; i += 256) {
    int e = e0 + i;
    unsigned int v = (unsigned int)(src[e] & 0xffff) | ((unsigned int)dst[e] << 16);
    stage1[i] = v;
    atomicAdd(&hist[(v >> 16) >> 7], 1);
  }
  __syncthreads();
  for (int b = tid; b < NB; b += 256) base_g[b] = atomicAdd(&cursor[b], hist[b]);
  int h0 = hist[2 * tid], h1 = hist[2 * tid + 1];
  int pv = h0 + h1;
  sc[tid] = pv;
  __syncthreads();
  #pragma unroll
  for (int off = 1; off < 256; off <<= 1) {
    int t = (tid >= off) ? sc[tid - off] : 0;
    __syncthreads();
    sc[tid] += t;
    __syncthreads();
  }
  int excl = sc[tid] - pv;
  base_l[2 * tid] = excl;
  base_l[2 * tid + 1] = excl + h0;
  __syncthreads();
  for (int i = tid; i < valid; i += 256) {
    unsigned int v = stage1[i];
    int b = (v >> 16) >> 7;
    int pos = base_l[b] + atomicAdd(&cl[b], 1);
    stage2[pos] = v;
  }
  __syncthreads();
  for (int i = tid; i < valid; i += 256) {
    unsigned int v = stage2[i];
    int b = (v >> 16) >> 7;
    int g = base_g[b] + (i - base_l[b]);
    if (g < BCAP) {
      part[(size_t)b * BCAP + g] = v;
    } else {
      int p = atomicAdd(ovf_cnt, 1);
      if (p < OVF_CAP) { ovf[2 * p] = (int)(v & 0xffffu); ovf[2 * p + 1] = (int)(v >> 16); }
    }
  }
}

// ---------------- phase 2: per-bucket ELL build in LDS ----------------
__global__ __launch_bounds__(256) void k_fill2(const unsigned int* __restrict__ part,
                                               const int* __restrict__ cursor,
                                               unsigned short* __restrict__ col,
                                               int* __restrict__ cnt,
                                               float* __restrict__ dinv,
                                               int* __restrict__ ovf_cnt,
                                               int* __restrict__ ovf, int N) {
  __shared__ unsigned short slab[128 * ELL_STRIDE];  // 16 KB
  __shared__ int cl[128];
  const int tid = threadIdx.x;
  const int b = blockIdx.x;
  if (tid < 128) cl[tid] = 0;
  __syncthreads();
  int count = cursor[b]; if (count > BCAP) count = BCAP;
  const unsigned int* p = part + (size_t)b * BCAP;
  for (int i = tid; i < count; i += 256) {
    unsigned int v = p[i];
    int row = (v >> 16) & 127;
    int k = atomicAdd(&cl[row], 1);
    if (k < ELL_STRIDE) {
      slab[row * ELL_STRIDE + k] = (unsigned short)(v & 0xffffu);
    } else {
      int q = atomicAdd(ovf_cnt, 1);
      if (q < OVF_CAP) { ovf[2 * q] = (int)(v & 0xffffu); ovf[2 * q + 1] = (int)(v >> 16); }
    }
  }
  __syncthreads();
  uint4* d4 = (uint4*)(col + (size_t)b * 128 * ELL_STRIDE);
  const uint4* s4 = (const uint4*)slab;
  #pragma unroll
  for (int i = 0; i < (128 * ELL_STRIDE * 2) / (16 * 256); ++i)
    d4[i * 256 + tid] = s4[i * 256 + tid];
  if (tid < 128) {
    int node = b * 128 + tid;
    if (node < N) {
      int c = cl[tid];
      cnt[node] = c;
      dinv[node] = rsqrtf((float)c + 1.0f);
    }
  }
}

// ---------------- MFMA GEMM -> chunk-major hb [4][M][32ch] ----------------
// B staged in LDS (two 64-row halves, +8-short row pad). Epilogue writes
// channel nt*16+m at hb[(nt>>1)][row][(nt&1)*16+m], pre-scaled by dinv[row].
template <int K, bool AF32>
__global__ __launch_bounds__(256) void k_gemm_mfma(const void* __restrict__ Xv,
                                                   const unsigned short* __restrict__ WT,
                                                   const float* __restrict__ dinv,
                                                   unsigned short* __restrict__ hb,
                                                   int M) {
  constexpr int KP = K + 8;
  __shared__ unsigned short Bs[64 * KP];
  const int tid = threadIdx.x;
  const int wave = tid >> 6, lane = tid & 63;
  const int q = lane >> 4, m = lane & 15;
  const int row0 = blockIdx.x * 64 + wave * 16;
  const bool active = row0 < M;
  const int arow = row0 + m;

  floatx4 acc[8];
  #pragma unroll
  for (int nt = 0; nt < 8; ++nt) acc[nt] = (floatx4){0.f, 0.f, 0.f, 0.f};
  bf16x8 af[K / 32];

  #pragma unroll
  for (int half = 0; half < 2; ++half) {
    __syncthreads();
    for (int c = tid; c < 64 * (K / 8); c += 256) {
      int r = c / (K / 8), ko = (c % (K / 8)) * 8;
      *(uint4*)(Bs + r * KP + ko) =
          *(const uint4*)(WT + (size_t)(half * 64 + r) * K + ko);
    }
    __syncthreads();
    if (active) {
      #pragma unroll
      for (int ks = 0; ks < K / 32; ++ks) {
        const int k0 = ks * 32 + q * 8;
        if (half == 0) {
          if (AF32) {
            const float* X = (const float*)Xv;
            float4 a0 = *(const float4*)(X + (size_t)arow * K + k0);
            float4 a1 = *(const float4*)(X + (size_t)arow * K + k0 + 4);
            af[ks] = (bf16x8){(short)f2bf(a0.x), (short)f2bf(a0.y),
                              (short)f2bf(a0.z), (short)f2bf(a0.w),
                              (short)f2bf(a1.x), (short)f2bf(a1.y),
                              (short)f2bf(a1.z), (short)f2bf(a1.w)};
          } else {
            af[ks] = *(const bf16x8*)((const unsigned short*)Xv +
                                      (size_t)arow * K + k0);
          }
        }
        #pragma unroll
        for (int ntl = 0; ntl < 4; ++ntl) {
          bf16x8 bf = *(const bf16x8*)(Bs + (ntl * 16 + m) * KP + k0);
          acc[half * 4 + ntl] =
              __builtin_amdgcn_mfma_f32_16x16x32_bf16(af[ks], bf, acc[half * 4 + ntl],
                                                      0, 0, 0);
        }
      }
    }
  }
  if (!active) return;
  #pragma unroll
  for (int r = 0; r < 4; ++r) {
    int grow = row0 + q * 4 + r;
    float di = dinv[grow];
    #pragma unroll
    for (int nt = 0; nt < 8; ++nt)
      hb[(size_t)(nt >> 1) * M * 32 + (size_t)grow * 32 + (nt & 1) * 16 + m] =
          f2bf(acc[nt][r] * di);
  }
}

// ---------------- XCD-affine 4-chunk ELL aggregate + bias + ReLU ----------
// chunk = blockIdx&3; block = 16 nodes. Quarter-wave = 1 node: 16 lanes own
// the chunk's 16 uints (2ch each). Col rows for all 16 nodes preloaded into
// LDS once (one coalesced uint4/thread); edge loop reads cols via ds_read
// (uniform in quarter = broadcast) -> 16 independent gathers in flight.
template <bool BF16OUT>
__global__ __launch_bounds__(256) void k_agg(const unsigned int* __restrict__ hb,
                                             const int* __restrict__ cnt,
                                             const unsigned short* __restrict__ col,
                                             const float* __restrict__ dinv,
                                             const int* __restrict__ ovf_cnt,
                                             const int* __restrict__ ovf,
                                             const float* __restrict__ bias,
                                             void* __restrict__ outv, int n) {
  __shared__ unsigned short cols[16][ELL_STRIDE];   // 2 KB
  const int tid = threadIdx.x;
  const int chunk = blockIdx.x & 3;
  const int nd0 = (blockIdx.x >> 2) * 16;
  {  // preload 16 x 64 cols: 2048 shorts = 256 threads x uint4
    int s = tid * 8;
    int node = nd0 + (s >> 6);
    uint4 v = make_uint4(0, 0, 0, 0);
    if (node < n) v = *(const uint4*)(col + (size_t)node * ELL_STRIDE + (s & 63));
    *(uint4*)&cols[s >> 6][s & 63] = v;
  }
  __syncthreads();
  const int d = nd0 + (tid >> 4);        // quarter-wave -> node
  const int u = tid & 15;                // uint (2ch) within 32-ch chunk
  if (d >= n) return;
  const unsigned int* slab = hb + (size_t)chunk * n * 16;
  const unsigned short* lc = cols[tid >> 4];

  // self-loop: hb pre-scaled by dinv -> hb[d]*dinv[d] = h[d]*dinv^2
  float2 acc = bfpair(slab[(size_t)d * 16 + u]);

  int m = cnt[d]; if (m > ELL_STRIDE) m = ELL_STRIDE;
  int k = 0;
  for (; k + 16 <= m; k += 16) {
    ushort4 ca = *(const ushort4*)(lc + k);
    ushort4 cb = *(const ushort4*)(lc + k + 4);
    ushort4 cc = *(const ushort4*)(lc + k + 8);
    ushort4 cd = *(const ushort4*)(lc + k + 12);
    unsigned int p0 = slab[(size_t)ca.x * 16 + u];
    unsigned int p1 = slab[(size_t)ca.y * 16 + u];
    unsigned int p2 = slab[(size_t)ca.z * 16 + u];
    unsigned int p3 = slab[(size_t)ca.w * 16 + u];
    unsigned int p4 = slab[(size_t)cb.x * 16 + u];
    unsigned int p5 = slab[(size_t)cb.y * 16 + u];
    unsigned int p6 = slab[(size_t)cb.z * 16 + u];
    unsigned int p7 = slab[(size_t)cb.w * 16 + u];
    unsigned int p8 = slab[(size_t)cc.x * 16 + u];
    unsigned int p9 = slab[(size_t)cc.y * 16 + u];
    unsigned int pa = slab[(size_t)cc.z * 16 + u];
    unsigned int pb = slab[(size_t)cc.w * 16 + u];
    unsigned int pc = slab[(size_t)cd.x * 16 + u];
    unsigned int pd = slab[(size_t)cd.y * 16 + u];
    unsigned int pe = slab[(size_t)cd.z * 16 + u];
    unsigned int pf = slab[(size_t)cd.w * 16 + u];
    float2 v0 = bfpair(p0), v1 = bfpair(p1), v2 = bfpair(p2), v3 = bfpair(p3);
    float2 v4 = bfpair(p4), v5 = bfpair(p5), v6 = bfpair(p6), v7 = bfpair(p7);
    acc.x += v0.x + v1.x + v2.x + v3.x + v4.x + v5.x + v6.x + v7.x;
    acc.y += v0.y + v1.y + v2.y + v3.y + v4.y + v5.y + v6.y + v7.y;
    float2 v8 = bfpair(p8), v9 = bfpair(p9), va = bfpair(pa), vb = bfpair(pb);
    float2 vc = bfpair(pc), vd = bfpair(pd), ve = bfpair(pe), vf = bfpair(pf);
    acc.x += v8.x + v9.x + va.x + vb.x + vc.x + vd.x + ve.x + vf.x;
    acc.y += v8.y + v9.y + va.y + vb.y + vc.y + vd.y + ve.y + vf.y;
  }
  for (; k + 8 <= m; k += 8) {
    ushort4 ca = *(const ushort4*)(lc + k);
    ushort4 cb = *(const ushort4*)(lc + k + 4);
    unsigned int p0 = slab[(size_t)ca.x * 16 + u];
    unsigned int p1 = slab[(size_t)ca.y * 16 + u];
    unsigned int p2 = slab[(size_t)ca.z * 16 + u];
    unsigned int p3 = slab[(size_t)ca.w * 16 + u];
    unsigned int p4 = slab[(size_t)cb.x * 16 + u];
    unsigned int p5 = slab[(size_t)cb.y * 16 + u];
    unsigned int p6 = slab[(size_t)cb.z * 16 + u];
    unsigned int p7 = slab[(size_t)cb.w * 16 + u];
    float2 v0 = bfpair(p0), v1 = bfpair(p1), v2 = bfpair(p2), v3 = bfpair(p3);
    float2 v4 = bfpair(p4), v5 = bfpair(p5), v6 = bfpair(p6), v7 = bfpair(p7);
    acc.x += v0.x + v1.x + v2.x + v3.x + v4.x + v5.x + v6.x + v7.x;
    acc.y += v0.y + v1.y + v2.y + v3.y + v4.y + v5.y + v6.y + v7.y;
  }
  for (; k < m; ++k) {
    int c = lc[k];
    float2 v = bfpair(slab[(size_t)c * 16 + u]);
    acc.x += v.x; acc.y += v.y;
  }
  int V = *ovf_cnt; if (V > OVF_CAP) V = OVF_CAP;
  for (int j = 0; j < V; ++j) {
    if (ovf[2 * j + 1] == d) {
      float2 v = bfpair(slab[(size_t)ovf[2 * j] * 16 + u]);
      acc.x += v.x; acc.y += v.y;
    }
  }
  float di = dinv[d];
  float2 bv = *(const float2*)(bias + chunk * 32 + 2 * u);
  float rx = fmaxf(di * acc.x + bv.x, 0.f);
  float ry = fmaxf(di * acc.y + bv.y, 0.f);
  if (BF16OUT) {   // row-major [N][128] bf16 (true channel order) for gemm2
    unsigned int pk = (unsigned int)f2bf(rx) | ((unsigned int)f2bf(ry) << 16);
    ((unsigned int*)outv)[(size_t)d * 64 + chunk * 16 + u] = pk;
  } else {
    *(float2*)((float*)outv + (size_t)d * 128 + chunk * 32 + 2 * u) =
        make_float2(rx, ry);
  }
}

// ---------------------------------------------------------------------------
extern "C" void kernel_launch(void* const* d_in, const int* in_sizes, int n_in,
                              void* d_out, int out_size, void* d_ws, size_t ws_size,
                              hipStream_t stream) {
  const float* x  = (const float*)d_in[0];
  const int*   ei = (const int*)d_in[1];
  const float* W1 = (const float*)d_in[2];
  const float* b1 = (const float*)d_in[3];
  const float* W2 = (const float*)d_in[4];
  const float* b2 = (const float*)d_in[5];
  float* out = (float*)d_out;

  const int IN_CH = 256;
  const int N = in_sizes[0] / IN_CH;   // 50000
  const int E = in_sizes[1] / 2;       // 1,600,000
  const int NB = (N + 127) >> 7;       // 391 buckets

  const int* src = ei;
  const int* dst = ei + E;

  char* ws = (char*)d_ws;
  size_t off = 0;
  auto carve = [&](size_t bytes) {
    void* p = ws + off;
    off += (bytes + 255) & ~(size_t)255;
    return p;
  };
  int*            cursor  = (int*)carve((size_t)NB * 4);
  int*            ovf_cnt = (int*)carve(4);
  int*            ovf     = (int*)carve((size_t)OVF_CAP * 2 * 4);
  int*            cnt     = (int*)carve((size_t)N * 4);
  float*          dinv    = (float*)carve((size_t)N * 4);
  unsigned short* col     = (unsigned short*)carve((size_t)N * ELL_STRIDE * 2); // 6.4MB
  unsigned short* hb      = (unsigned short*)carve((size_t)N * 128 * 2);        // [4][N][32] 12.8MB
  unsigned short* WT1     = (unsigned short*)carve(128 * 256 * 2);
  unsigned short* WT2     = (unsigned short*)carve(128 * 128 * 2);
  // union: part (dead after k_fill2) aliases aggbuf (bf16, by k_agg#1)
  char*           unionp  = (char*)carve((size_t)NB * BCAP * 4);   // 12.8MB
  unsigned int*   part    = (unsigned int*)unionp;
  unsigned short* aggbuf  = (unsigned short*)unionp;               // [N][128] bf16

  k_cvt_w<<<(128 * 256 + 128 * 128 + 255) / 256, 256, 0, stream>>>(
      W1, W2, WT1, WT2, cursor, ovf_cnt, NB);
  k_part <<<(E + PART_T - 1) / PART_T, 256, 0, stream>>>(src, dst, cursor, part,
                                                         ovf_cnt, ovf, E, NB);
  k_fill2<<<NB, 256, 0, stream>>>(part, cursor, col, cnt, dinv, ovf_cnt, ovf, N);

  int gblocks = (N + 63) / 64;           // 782
  int ablocks = 4 * ((N + 15) / 16);     // 4 chunks x 3125
  k_gemm_mfma<256, true ><<<gblocks, 256, 0, stream>>>(x, WT1, dinv, hb, N);
  k_agg<true ><<<ablocks, 256, 0, stream>>>((const unsigned int*)hb, cnt, col, dinv,
                                            ovf_cnt, ovf, b1, aggbuf, N);
  k_gemm_mfma<128, false><<<gblocks, 256, 0, stream>>>(aggbuf, WT2, dinv, hb, N);
  k_agg<false><<<ablocks, 256, 0, stream>>>((const unsigned int*)hb, cnt, col, dinv,
                                            ovf_cnt, ovf, b2, out, N);
}